// Round 4
// baseline (435.374 us; speedup 1.0000x reference)
//
#include <hip/hip_runtime.h>

#define D_NODE   128
#define N_BASIS  9
#define D_EDGE   128

#define BLOCK_C 256
#define TPT     4                      // triples per thread
#define CHUNK   (BLOCK_C * TPT)        // 1024 triples per block
#define WAVE_T  (64 * TPT)             // 256 triples per wave slab
#define SLAB_F  (WAVE_T * N_BASIS)     // 2304 floats per wave slab (9216 B)
#define SEG_CAP 256                    // LDS segment-range capacity

typedef _Float16 half8 __attribute__((ext_vector_type(8)));

#define AS1(p) ((const __attribute__((address_space(1))) void*)(p))
#define AS3(p) ((__attribute__((address_space(3))) void*)(p))

__device__ __forceinline__ float fast_sigmoid(float x) {
    return __builtin_amdgcn_rcpf(1.0f + __expf(-x));
}

// Kernel A: atoms8[a][0..7] / atoms1[a] = sigmoid(node_feat[a,:] @ W_atom[:,b] + b_atom[b]).
// Split tables: 16-B rows (never straddle a line, 80 KB total) + 10-KB scalar table.
__global__ __launch_bounds__(256) void atoms_kernel(
    const float* __restrict__ node_feat,
    const float* __restrict__ W_atom,
    const float* __restrict__ b_atom,
    _Float16* __restrict__ atoms8,
    _Float16* __restrict__ atoms1, int n_atoms)
{
    __shared__ float sW[D_NODE * N_BASIS];
    for (int t = threadIdx.x; t < D_NODE * N_BASIS; t += 256)
        sW[t] = W_atom[t];
    __syncthreads();
    int idx = blockIdx.x * 256 + threadIdx.x;
    int total = n_atoms * N_BASIS;
    if (idx >= total) return;
    int a = idx / N_BASIS;
    int b = idx - a * N_BASIS;
    const float* row = node_feat + a * D_NODE;
    float acc = b_atom[b];
#pragma unroll 8
    for (int i = 0; i < D_NODE; ++i)
        acc += row[i] * sW[i * N_BASIS + b];
    _Float16 v = (_Float16)fast_sigmoid(acc);
    if (b < 8) atoms8[a * 8 + b] = v;
    else       atoms1[a] = v;
}

#define FLUSH_RUN()                                                          \
    do {                                                                     \
        if (use_lds) {                                                       \
            float* dst_ = lacc + (cur - seg_first) * N_BASIS;                \
            _Pragma("unroll")                                                \
            for (int k_ = 0; k_ < N_BASIS; ++k_)                             \
                atomicAdd(&dst_[k_], sum[k_]);                               \
        } else {                                                             \
            float* dst_ = new_bonds + (size_t)cur * N_BASIS;                 \
            _Pragma("unroll")                                                \
            for (int k_ = 0; k_ < N_BASIS; ++k_)                             \
                unsafeAtomicAdd(&dst_[k_], sum[k_]);                         \
        }                                                                    \
    } while (0)

// Kernel C: streaming segmented reduction over sorted triples.
// Per-WAVE LDS staging of the tb slab (coalesced global_load_lds, no extra
// barrier: the lacc-init __syncthreads drains vmcnt). Gathers hit small
// L1/L2-resident tables only (graph_dst 800 KB, atoms8 80 KB, atoms1 10 KB).
__global__ __launch_bounds__(BLOCK_C) void triple_kernel(
    const float* __restrict__ three_basis,
    const _Float16* __restrict__ atoms8,
    const _Float16* __restrict__ atoms1,
    const int*   __restrict__ graph_dst,
    const int*   __restrict__ lg_dst,
    const int*   __restrict__ seg,
    float* __restrict__ new_bonds,
    int n_triples)
{
    __shared__ float stb[4 * SLAB_F];          // 36864 B staged three_basis
    __shared__ float lacc[SEG_CAP * N_BASIS];  // 9216 B
    __shared__ int sh_first, sh_last;

    const int tid  = threadIdx.x;
    const int wave = tid >> 6;
    const int lane = tid & 63;
    const int chunk_start = blockIdx.x * CHUNK;
    const int slab_start  = chunk_start + wave * WAVE_T;
    const int t0 = slab_start + lane * TPT;    // == chunk_start + tid*TPT

    float* mystb = stb + wave * SLAB_F;
    const bool staged = (slab_start + WAVE_T <= n_triples);  // wave-uniform
    if (staged) {
        const char* gsrc = (const char*)three_basis + (size_t)slab_start * (N_BASIS * 4);
#pragma unroll
        for (int i = 0; i < 9; ++i) {
            // LDS dest wave-uniform; HW adds lane*16. Global src per-lane, coalesced.
            __builtin_amdgcn_global_load_lds(
                AS1(gsrc + (size_t)(i * 64 + lane) * 16),
                AS3((char*)mystb + i * 1024),
                16, 0, 0);
        }
    }

    if (tid == 0) sh_first = seg[chunk_start];
    if (tid == BLOCK_C - 1) {
        int last = chunk_start + CHUNK;
        if (last > n_triples) last = n_triples;
        sh_last = seg[last - 1];
    }
    for (int i = tid; i < SEG_CAP * N_BASIS; i += BLOCK_C)
        lacc[i] = 0.0f;
    __syncthreads();   // compiler drains vmcnt (incl. our wave's DMA) before s_barrier

    const int seg_first = sh_first;
    const int range = sh_last - seg_first + 1;
    const bool use_lds = (range <= SEG_CAP);

    if (t0 + TPT <= n_triples) {
        // ---- fast path: everything compile-time indexed ----
        const int4 sg4 = *(const int4*)(seg + t0);
        const int4 ld4 = *(const int4*)(lg_dst + t0);
        int sgs[TPT] = { sg4.x, sg4.y, sg4.z, sg4.w };
        int ai[TPT];
        ai[0] = graph_dst[ld4.x];
        ai[1] = graph_dst[ld4.y];
        ai[2] = graph_dst[ld4.z];
        ai[3] = graph_dst[ld4.w];

        // issue all row gathers up front (independent, 1 aligned line each)
        half8 hh[TPT];
        _Float16 h8[TPT];
#pragma unroll
        for (int i = 0; i < TPT; ++i) {
            hh[i] = *(const half8*)(atoms8 + (size_t)ai[i] * 8);
            h8[i] = atoms1[ai[i]];
        }

        // tb: LDS (staged) or global fallback (partial last slab, generic shapes)
        float tb[TPT * N_BASIS];
        if (staged) {
            const float* tbl = mystb + lane * (TPT * N_BASIS);
#pragma unroll
            for (int q = 0; q < 9; ++q)
                *(float4*)&tb[q * 4] = *(const float4*)(tbl + q * 4);
        } else {
            const float4* tb4 = (const float4*)(three_basis + (size_t)t0 * N_BASIS);
#pragma unroll
            for (int q = 0; q < 9; ++q)
                *(float4*)&tb[q * 4] = tb4[q];
        }

        float sum[N_BASIS];
        int cur = sgs[0];
#pragma unroll
        for (int k = 0; k < N_BASIS; ++k) sum[k] = 0.0f;

#pragma unroll
        for (int i = 0; i < TPT; ++i) {
            if (sgs[i] != cur) {
                FLUSH_RUN();
                cur = sgs[i];
#pragma unroll
                for (int k = 0; k < N_BASIS; ++k) sum[k] = 0.0f;
            }
#pragma unroll
            for (int k = 0; k < 8; ++k)
                sum[k] += tb[i * N_BASIS + k] * (float)hh[i][k];
            sum[8] += tb[i * N_BASIS + 8] * (float)h8[i];
        }
        FLUSH_RUN();
    } else if (t0 < n_triples) {
        // ---- array-free tail path (unused when n_triples % 4 == 0) ----
        for (int t = t0; t < n_triples; ++t) {
            int cur = seg[t];
            int a = graph_dst[lg_dst[t]];
            const float* tbr = three_basis + (size_t)t * N_BASIS;
            const _Float16* ar = atoms8 + (size_t)a * 8;
            float sum[N_BASIS];
#pragma unroll
            for (int k = 0; k < 8; ++k) sum[k] = tbr[k] * (float)ar[k];
            sum[8] = tbr[8] * (float)atoms1[a];
            FLUSH_RUN();
        }
    }

    __syncthreads();

    if (use_lds) {
        int total = range * N_BASIS;
        for (int idx = tid; idx < total; idx += BLOCK_C) {
            int r = idx / N_BASIS;
            int k = idx - r * N_BASIS;
            float v = lacc[idx];
            int s = seg_first + r;
            if (r == 0 || r == range - 1) {
                if (v != 0.0f)
                    unsafeAtomicAdd(&new_bonds[(size_t)s * N_BASIS + k], v);
            } else {
                new_bonds[(size_t)s * N_BASIS + k] = v;   // fully owned
            }
        }
    }
}

// Kernel D: per-edge gated MLP 9 -> 128 + residual. 32 edges/block; W_gate,
// W_sig and the nb tile staged in LDS (kills the per-group W re-fetch that
// dominated this kernel's TA-request budget: ~61 -> ~17 requests/edge).
__global__ __launch_bounds__(256) void mlp_kernel(
    const float* __restrict__ edge_feat,
    const float* __restrict__ new_bonds,
    const float* __restrict__ W_gate, const float* __restrict__ b_gate,
    const float* __restrict__ W_sig,  const float* __restrict__ b_sig,
    float* __restrict__ out, int n_edges)
{
    __shared__ float sWg[N_BASIS * D_EDGE];   // 4608 B
    __shared__ float sWs[N_BASIS * D_EDGE];   // 4608 B
    __shared__ float snb[32 * N_BASIS];       // 1152 B

    const int tid = threadIdx.x;
    const int e_base = blockIdx.x * 32;

    for (int i = tid; i < N_BASIS * D_EDGE; i += 256) {
        sWg[i] = W_gate[i];
        sWs[i] = W_sig[i];
    }
    {
        int nv = n_edges - e_base;
        if (nv > 32) nv = 32;
        for (int i = tid; i < nv * N_BASIS; i += 256)
            snb[i] = new_bonds[(size_t)e_base * N_BASIS + i];
    }
    __syncthreads();

    const int grp = tid >> 5;                // 8 groups of 32 lanes
    const int c   = (tid & 31) * 4;          // channel base
    const int e0  = e_base + grp * 4;
    if (e0 >= n_edges) return;
    const int nvalid = (n_edges - e0) < 4 ? (n_edges - e0) : 4;

    float nb[4][N_BASIS];
#pragma unroll
    for (int j = 0; j < 4; ++j) {
        int jj = (j < nvalid) ? j : 0;
#pragma unroll
        for (int k = 0; k < N_BASIS; ++k)
            nb[j][k] = snb[(grp * 4 + jj) * N_BASIS + k];   // LDS broadcast
    }

    float4 bg = *(const float4*)(b_gate + c);
    float4 bs = *(const float4*)(b_sig + c);
    float4 g[4], s[4];
#pragma unroll
    for (int j = 0; j < 4; ++j) { g[j] = bg; s[j] = bs; }

#pragma unroll
    for (int k = 0; k < N_BASIS; ++k) {
        float4 wg = *(const float4*)&sWg[k * D_EDGE + c];
        float4 ws = *(const float4*)&sWs[k * D_EDGE + c];
#pragma unroll
        for (int j = 0; j < 4; ++j) {
            g[j].x += nb[j][k] * wg.x; g[j].y += nb[j][k] * wg.y;
            g[j].z += nb[j][k] * wg.z; g[j].w += nb[j][k] * wg.w;
            s[j].x += nb[j][k] * ws.x; s[j].y += nb[j][k] * ws.y;
            s[j].z += nb[j][k] * ws.z; s[j].w += nb[j][k] * ws.w;
        }
    }

#pragma unroll
    for (int j = 0; j < 4; ++j) {
        if (j < nvalid) {
            int e = e0 + j;
            float4 ef = *(const float4*)(edge_feat + (size_t)e * D_EDGE + c);
            float4 o;
            o.x = ef.x + g[j].x * fast_sigmoid(g[j].x) * fast_sigmoid(s[j].x);
            o.y = ef.y + g[j].y * fast_sigmoid(g[j].y) * fast_sigmoid(s[j].y);
            o.z = ef.z + g[j].z * fast_sigmoid(g[j].z) * fast_sigmoid(s[j].z);
            o.w = ef.w + g[j].w * fast_sigmoid(g[j].w) * fast_sigmoid(s[j].w);
            *(float4*)(out + (size_t)e * D_EDGE + c) = o;
        }
    }
}

extern "C" void kernel_launch(void* const* d_in, const int* in_sizes, int n_in,
                              void* d_out, int out_size, void* d_ws, size_t ws_size,
                              hipStream_t stream) {
    const float* node_feat   = (const float*)d_in[0];
    const float* edge_feat   = (const float*)d_in[1];
    const float* three_basis = (const float*)d_in[2];
    // d_in[3] three_cutoff: dead code in reference
    const float* W_atom      = (const float*)d_in[4];
    const float* b_atom      = (const float*)d_in[5];
    const float* W_gate      = (const float*)d_in[6];
    const float* b_gate      = (const float*)d_in[7];
    const float* W_sig       = (const float*)d_in[8];
    const float* b_sig       = (const float*)d_in[9];
    const int*   graph_dst   = (const int*)d_in[10];
    // d_in[11] lg_src: dead code in reference
    const int*   lg_dst      = (const int*)d_in[12];
    const int*   seg         = (const int*)d_in[13];

    int n_atoms   = in_sizes[0] / D_NODE;
    int n_edges   = in_sizes[1] / D_EDGE;
    int n_triples = in_sizes[2] / N_BASIS;

    // ws layout: atoms8 fp16 [n_atoms*8] | atoms1 fp16 [n_atoms] | new_bonds f32
    size_t a8_bytes = ((size_t)n_atoms * 8 * sizeof(_Float16) + 255) & ~(size_t)255;
    size_t a1_bytes = ((size_t)n_atoms * sizeof(_Float16) + 255) & ~(size_t)255;
    size_t nb_bytes = (size_t)n_edges * N_BASIS * sizeof(float);

    _Float16* atoms8 = (_Float16*)d_ws;
    _Float16* atoms1 = (_Float16*)((char*)d_ws + a8_bytes);
    float* new_bonds = (float*)((char*)d_ws + a8_bytes + a1_bytes);

    hipMemsetAsync(new_bonds, 0, nb_bytes, stream);

    atoms_kernel<<<(n_atoms * N_BASIS + 255) / 256, 256, 0, stream>>>(
        node_feat, W_atom, b_atom, atoms8, atoms1, n_atoms);

    triple_kernel<<<(n_triples + CHUNK - 1) / CHUNK, BLOCK_C, 0, stream>>>(
        three_basis, atoms8, atoms1, graph_dst, lg_dst, seg, new_bonds, n_triples);

    mlp_kernel<<<(n_edges + 31) / 32, 256, 0, stream>>>(
        edge_feat, new_bonds, W_gate, b_gate, W_sig, b_sig, (float*)d_out, n_edges);
}